// Round 3
// baseline (471.648 us; speedup 1.0000x reference)
//
#include <hip/hip_runtime.h>

#define T_TOKENS 2048
#define HIDDEN   2048
#define NEXPERT  32
#define TOPK     4
#define INTER    768
#define NPAIRS   (T_TOKENS*TOPK)   /* 8192 */
#define BM       128
#define BK       32
#define MT_MAX   95                /* sum ceil(cnt/128) <= 64 + 31 */
#define NT1      24                /* 768/32 gated col-tiles (BN=64: 32 g + 32 u) */
#define NT2      32                /* 2048/64 out col-tiles */
#define NK1      (HIDDEN/BK)       /* 64 */
#define NK2      (INTER/BK)        /* 24 */

typedef short  bh8 __attribute__((ext_vector_type(8)));   // 8 bf16
typedef float  fx4 __attribute__((ext_vector_type(4)));

#define AS1 __attribute__((address_space(1)))
#define AS3 __attribute__((address_space(3)))

__device__ __forceinline__ void gload_lds16(const void* g, const void* lds_generic){
    __builtin_amdgcn_global_load_lds(
        (const AS1 void*)(unsigned long long)g,
        (AS3 void*)(unsigned int)(unsigned long long)lds_generic,
        16, 0, 0);
}

// pack two f32 -> two bf16 (round-half-up: 2 adds + 1 v_perm); lo=first arg
__device__ __forceinline__ unsigned int pack2bf(float a, float b){
    unsigned ua = __float_as_uint(a) + 0x8000u;
    unsigned ub = __float_as_uint(b) + 0x8000u;
    return __builtin_amdgcn_perm(ub, ua, 0x07060302u);
}
__device__ __forceinline__ unsigned short f2bfu(float f){
    return (unsigned short)((__float_as_uint(f) + 0x8000u) >> 16);
}

/* ---------------- x -> bf16 ---------------- */
__global__ void cvt_x_k(const float* __restrict__ x, unsigned short* __restrict__ xb){
    int i = (blockIdx.x*256 + threadIdx.x)*8;
    float4 a = *(const float4*)(x+i);
    float4 b = *(const float4*)(x+i+4);
    uint4 o;
    o.x = pack2bf(a.x,a.y); o.y = pack2bf(a.z,a.w);
    o.z = pack2bf(b.x,b.y); o.w = pack2bf(b.z,b.w);
    *(uint4*)(xb+i) = o;
}

/* ---------------- router ---------------- */
__global__ void router_k(const float* __restrict__ x, const float* __restrict__ gate,
                         int* __restrict__ topk_id, float* __restrict__ topk_w,
                         int* __restrict__ counts){
    const int t = blockIdx.x;
    const int l = threadIdx.x;
    const float* xr = x + (size_t)t*HIDDEN;
    float acc[NEXPERT];
#pragma unroll
    for (int e=0;e<NEXPERT;e++) acc[e]=0.f;
    for (int d=l; d<HIDDEN; d+=64){
        float xv = xr[d];
        const float4* g4 = (const float4*)(gate + (size_t)d*NEXPERT);
#pragma unroll
        for (int i=0;i<8;i++){
            float4 g = g4[i];
            acc[i*4+0] += xv*g.x; acc[i*4+1] += xv*g.y;
            acc[i*4+2] += xv*g.z; acc[i*4+3] += xv*g.w;
        }
    }
#pragma unroll
    for (int e=0;e<NEXPERT;e++){
#pragma unroll
        for (int m=1;m<64;m<<=1) acc[e] += __shfl_xor(acc[e], m, 64);
    }
    int ids[TOPK]; float lv[TOPK];
#pragma unroll
    for (int k=0;k<TOPK;k++){
        float m=-1e30f; int mi=0;
#pragma unroll
        for (int e=0;e<NEXPERT;e++){ if (acc[e]>m){ m=acc[e]; mi=e; } }
        ids[k]=mi; lv[k]=m; acc[mi]=-1e30f;
    }
    float ex[TOPK]; float s=0.f;
#pragma unroll
    for (int k=0;k<TOPK;k++){ ex[k]=__expf(lv[k]-lv[0]); s+=ex[k]; }
    if (l==0){
        float inv = 1.f/s;
#pragma unroll
        for (int k=0;k<TOPK;k++){
            topk_id[t*TOPK+k]=ids[k];
            topk_w[t*TOPK+k]=ex[k]*inv;
            atomicAdd(&counts[ids[k]],1);
        }
    }
}

/* ---------------- schedule ---------------- */
__global__ void sched_k(const int* __restrict__ counts, int* __restrict__ offs,
                        int* __restrict__ cursors, int* __restrict__ nmt,
                        int* __restrict__ te, int* __restrict__ tr0, int* __restrict__ trn){
    if (threadIdx.x==0 && blockIdx.x==0){
        int tot=0, nm=0;
        for (int e=0;e<NEXPERT;e++){
            int c = counts[e];
            offs[e]=tot; cursors[e]=tot;
            for (int s=0;s<c;s+=BM){
                te[nm]=e; tr0[nm]=tot+s; trn[nm]=(c-s)<BM?(c-s):BM; nm++;
            }
            tot+=c;
        }
        *nmt = nm;
    }
}

/* ---------------- scatter ---------------- */
__global__ void scatter_k(const int* __restrict__ topk_id, const float* __restrict__ topk_w,
                          int* __restrict__ cursors, int* __restrict__ pair_tok,
                          float* __restrict__ pair_w){
    int g = blockIdx.x*256 + threadIdx.x;
    int e = topk_id[g];
    float w = topk_w[g];
    int pos = atomicAdd(&cursors[e],1);
    pair_tok[pos] = g>>2;
    pair_w[pos]  = w;
}

/* shared per-GEMM tile-id decode: bijective XCD-chunked swizzle, mt innermost */
#define TILE_DECODE(NT)                                            \
    const int nwg = gridDim.x;                                     \
    const int q = nwg>>3, r = nwg&7;                               \
    const int xcd = blockIdx.x & 7, bidx = blockIdx.x >> 3;        \
    const int L = (xcd<r ? xcd*(q+1) : r*(q+1)+(xcd-r)*q) + bidx;  \
    const int mt = L % MT_MAX, nt = L / MT_MAX;                    \
    if (mt >= *nmt) return;                                        \
    const int e = te[mt], row0 = tr0[mt], rows = trn[mt];

/* ============== grouped GEMM1: xb(bf16) x gup(f32->bf16) -> gated(bf16) ============== */
__global__ __launch_bounds__(256) void gemm1_k(
        const unsigned short* __restrict__ xb, const float* __restrict__ gup,
        const int* __restrict__ nmt, const int* __restrict__ te,
        const int* __restrict__ tr0, const int* __restrict__ trn,
        const int* __restrict__ pair_tok, const float* __restrict__ pair_w,
        unsigned short* __restrict__ gated){
    __shared__ __align__(16) unsigned short As[2][BM*32]; // 2 x 8KB, linear 64B rows
    __shared__ __align__(16) unsigned short Bs[2][64*40]; // 2 x 5KB, [col][40] pitch 80B
    __shared__ int   s_tok[BM];
    __shared__ float s_w[BM];

    TILE_DECODE(NT1)
    const int n0 = nt*32;

    const int t = threadIdx.x;
    if (t < BM){
        int p = row0 + t; if (p > NPAIRS-1) p = NPAIRS-1;
        s_tok[t] = pair_tok[p];
        s_w[t]   = pair_w[p];
    }
    __syncthreads();

    const int w = t>>6, lane = t&63;
    const int l15 = lane & 15, kb = lane >> 4;
    const int sA = (l15>>1)&3;

    // A DMA (gathered bf16 x rows)
    const int arow0 = w*16 + (lane>>2);
    const int arow1 = 64 + arow0;
    const int ck0 = (lane&3) ^ ((lane>>3)&3);
    const unsigned short* asrc0 = xb + (size_t)s_tok[arow0]*HIDDEN + ck0*8;
    const unsigned short* asrc1 = xb + (size_t)s_tok[arow1]*HIDDEN + ck0*8;

    // B staging: thread -> 2 rows x 4 cols
    const int col4 = (t&15)*4;
    const int bd0  = (t>>4)*2;
    const int sB   = (col4>>3)&3;
    const unsigned wb = (unsigned)(col4*80 + (((bd0>>3) ^ sB)<<4) + (bd0&7)*2);
    const int fc = (col4 < 32) ? (n0 + col4) : (736 + n0 + col4);
    const float* bsrc = gup + (size_t)e*HIDDEN*(2*INTER) + (size_t)bd0*(2*INTER) + fc;

    fx4 acc[2][4];
#pragma unroll
    for (int i=0;i<2;i++)
#pragma unroll
        for (int j=0;j<4;j++) acc[i][j] = (fx4)0.f;

    // prologue: stage k=0
    float4 rv0 = *(const float4*)(bsrc);
    float4 rv1 = *(const float4*)(bsrc + 2*INTER);
    gload_lds16(asrc0, &As[0][(w*16)*32]);
    gload_lds16(asrc1, &As[0][(64+w*16)*32]);
    __syncthreads();                       // drains A(0) DMA
    {
        char* bw = (char*)Bs[0];
        *(unsigned*)(bw + wb      ) = pack2bf(rv0.x, rv1.x);
        *(unsigned*)(bw + wb +  80) = pack2bf(rv0.y, rv1.y);
        *(unsigned*)(bw + wb + 160) = pack2bf(rv0.z, rv1.z);
        *(unsigned*)(bw + wb + 240) = pack2bf(rv0.w, rv1.w);
    }
    __syncthreads();                       // Bs[0] visible

#define G1_STEP(KK, CUR, NXT) do{                                              \
    const int _kn = (KK)+1;                                                    \
    if (_kn < NK1){                                                            \
        const float* _b2 = bsrc + (size_t)_kn*BK*(2*INTER);                    \
        rv0 = *(const float4*)(_b2);                                           \
        rv1 = *(const float4*)(_b2 + 2*INTER);                                 \
        gload_lds16(asrc0 + _kn*BK, &As[NXT][(w*16)*32]);                      \
        gload_lds16(asrc1 + _kn*BK, &As[NXT][(64+w*16)*32]);                   \
    }                                                                          \
    {   const unsigned short* _Ak = As[CUR];                                   \
        const char* _Bk = (const char*)Bs[CUR];                                \
        bh8 _a0 = *(const bh8*)(_Ak + (w*32+l15)*32    + ((kb ^ sA)<<3));      \
        bh8 _a1 = *(const bh8*)(_Ak + (w*32+16+l15)*32 + ((kb ^ sA)<<3));      \
        _Pragma("unroll")                                                      \
        for (int c=0;c<4;c++){                                                 \
            const int bc = c*16 + l15;                                         \
            bh8 _b = *(const bh8*)(_Bk + bc*80 + ((kb ^ ((bc>>3)&3))<<4));     \
            acc[0][c] = __builtin_amdgcn_mfma_f32_16x16x32_bf16(_a0,_b,acc[0][c],0,0,0); \
            acc[1][c] = __builtin_amdgcn_mfma_f32_16x16x32_bf16(_a1,_b,acc[1][c],0,0,0); \
        }                                                                      \
    }                                                                          \
    if (_kn < NK1){                                                            \
        char* _bw = (char*)Bs[NXT];                                            \
        *(unsigned*)(_bw + wb      ) = pack2bf(rv0.x, rv1.x);                  \
        *(unsigned*)(_bw + wb +  80) = pack2bf(rv0.y, rv1.y);                  \
        *(unsigned*)(_bw + wb + 160) = pack2bf(rv0.z, rv1.z);                  \
        *(unsigned*)(_bw + wb + 240) = pack2bf(rv0.w, rv1.w);                  \
    }                                                                          \
    __syncthreads();                                                           \
}while(0)

    for (int k2=0; k2<NK1; k2+=2){
        G1_STEP(k2,   0, 1);
        G1_STEP(k2+1, 1, 0);
    }
#undef G1_STEP

    // epilogue: gated = silu(g)*u*router_w (32 cols: c=0,1 gate / c=2,3 up)
    const int rbase = w*32 + kb*4;
#pragma unroll
    for (int mr=0;mr<2;mr++){
#pragma unroll
        for (int qq=0;qq<4;qq++){
            int row = rbase + mr*16 + qq;
            if (row < rows){
                float wgt = s_w[row];
                size_t prow = (size_t)(row0 + row)*INTER + n0 + l15;
#pragma unroll
                for (int c=0;c<2;c++){
                    float g = acc[mr][c][qq], u = acc[mr][c+2][qq];
                    float sil = g / (1.f + __expf(-g));
                    gated[prow + c*16] = f2bfu(sil*u*wgt);
                }
            }
        }
    }
}

/* ============== grouped GEMM2: gated(bf16) x down(f32->bf16) -> out (atomic f32) ============== */
__global__ __launch_bounds__(256) void gemm2_k(
        const unsigned short* __restrict__ gated, const float* __restrict__ down,
        const int* __restrict__ nmt, const int* __restrict__ te,
        const int* __restrict__ tr0, const int* __restrict__ trn,
        const int* __restrict__ pair_tok, float* __restrict__ out){
    __shared__ __align__(16) unsigned short As[2][BM*32];
    __shared__ __align__(16) unsigned short Bs[2][64*40];
    __shared__ int s_tok[BM];

    TILE_DECODE(NT2)
    const int n0 = nt*64;

    const int t = threadIdx.x;
    if (t < BM){
        int p = row0 + t; if (p > NPAIRS-1) p = NPAIRS-1;
        s_tok[t] = pair_tok[p];
    }
    __syncthreads();

    const int w = t>>6, lane = t&63;
    const int l15 = lane & 15, kb = lane >> 4;
    const int sA = (l15>>1)&3;

    const int arow0 = w*16 + (lane>>2);
    const int arow1 = 64 + arow0;
    const int ck0 = (lane&3) ^ ((lane>>3)&3);
    int ap0 = row0 + arow0; if (ap0 > NPAIRS-1) ap0 = NPAIRS-1;
    int ap1 = row0 + arow1; if (ap1 > NPAIRS-1) ap1 = NPAIRS-1;
    const unsigned short* asrc0 = gated + (size_t)ap0*INTER + ck0*8;
    const unsigned short* asrc1 = gated + (size_t)ap1*INTER + ck0*8;

    const int col4 = (t&15)*4;
    const int bd0  = (t>>4)*2;
    const int sB   = (col4>>3)&3;
    const unsigned wb = (unsigned)(col4*80 + (((bd0>>3) ^ sB)<<4) + (bd0&7)*2);
    const float* bsrc = down + (size_t)e*INTER*HIDDEN + (size_t)bd0*HIDDEN + (n0 + col4);

    fx4 acc[2][4];
#pragma unroll
    for (int i=0;i<2;i++)
#pragma unroll
        for (int j=0;j<4;j++) acc[i][j] = (fx4)0.f;

    float4 rv0 = *(const float4*)(bsrc);
    float4 rv1 = *(const float4*)(bsrc + HIDDEN);
    gload_lds16(asrc0, &As[0][(w*16)*32]);
    gload_lds16(asrc1, &As[0][(64+w*16)*32]);
    __syncthreads();
    {
        char* bw = (char*)Bs[0];
        *(unsigned*)(bw + wb      ) = pack2bf(rv0.x, rv1.x);
        *(unsigned*)(bw + wb +  80) = pack2bf(rv0.y, rv1.y);
        *(unsigned*)(bw + wb + 160) = pack2bf(rv0.z, rv1.z);
        *(unsigned*)(bw + wb + 240) = pack2bf(rv0.w, rv1.w);
    }
    __syncthreads();

#define G2_STEP(KK, CUR, NXT) do{                                              \
    const int _kn = (KK)+1;                                                    \
    if (_kn < NK2){                                                            \
        const float* _b2 = bsrc + (size_t)_kn*BK*HIDDEN;                       \
        rv0 = *(const float4*)(_b2);                                           \
        rv1 = *(const float4*)(_b2 + HIDDEN);                                  \
        gload_lds16(asrc0 + _kn*BK, &As[NXT][(w*16)*32]);                      \
        gload_lds16(asrc1 + _kn*BK, &As[NXT][(64+w*16)*32]);                   \
    }                                                                          \
    {   const unsigned short* _Ak = As[CUR];                                   \
        const char* _Bk = (const char*)Bs[CUR];                                \
        bh8 _a0 = *(const bh8*)(_Ak + (w*32+l15)*32    + ((kb ^ sA)<<3));      \
        bh8 _a1 = *(const bh8*)(_Ak + (w*32+16+l15)*32 + ((kb ^ sA)<<3));      \
        _Pragma("unroll")                                                      \
        for (int c=0;c<4;c++){                                                 \
            const int bc = c*16 + l15;                                         \
            bh8 _b = *(const bh8*)(_Bk + bc*80 + ((kb ^ ((bc>>3)&3))<<4));     \
            acc[0][c] = __builtin_amdgcn_mfma_f32_16x16x32_bf16(_a0,_b,acc[0][c],0,0,0); \
            acc[1][c] = __builtin_amdgcn_mfma_f32_16x16x32_bf16(_a1,_b,acc[1][c],0,0,0); \
        }                                                                      \
    }                                                                          \
    if (_kn < NK2){                                                            \
        char* _bw = (char*)Bs[NXT];                                            \
        *(unsigned*)(_bw + wb      ) = pack2bf(rv0.x, rv1.x);                  \
        *(unsigned*)(_bw + wb +  80) = pack2bf(rv0.y, rv1.y);                  \
        *(unsigned*)(_bw + wb + 160) = pack2bf(rv0.z, rv1.z);                  \
        *(unsigned*)(_bw + wb + 240) = pack2bf(rv0.w, rv1.w);                  \
    }                                                                          \
    __syncthreads();                                                           \
}while(0)

    for (int k2=0; k2<NK2; k2+=2){
        G2_STEP(k2,   0, 1);
        G2_STEP(k2+1, 1, 0);
    }
#undef G2_STEP

    const int rbase = w*32 + kb*4;
#pragma unroll
    for (int mr=0;mr<2;mr++){
#pragma unroll
        for (int qq=0;qq<4;qq++){
            int row = rbase + mr*16 + qq;
            if (row < rows){
                float* orow = out + (size_t)s_tok[row]*HIDDEN + n0 + l15;
#pragma unroll
                for (int c=0;c<4;c++)
                    atomicAdd(orow + c*16, acc[mr][c][qq]);
            }
        }
    }
}

/* ---------------- host launch ---------------- */
extern "C" void kernel_launch(void* const* d_in, const int* in_sizes, int n_in,
                              void* d_out, int out_size, void* d_ws, size_t ws_size,
                              hipStream_t stream){
    const float* x    = (const float*)d_in[0];
    const float* gate = (const float*)d_in[1];
    const float* gup  = (const float*)d_in[2];
    const float* down = (const float*)d_in[3];
    float* out = (float*)d_out;
    char*  ws  = (char*)d_ws;

    int*   topk_id  = (int*)  (ws + 0x00000);
    float* topk_w   = (float*)(ws + 0x08000);
    int*   counts   = (int*)  (ws + 0x10000);
    int*   cursors  = (int*)  (ws + 0x10080);
    int*   offs     = (int*)  (ws + 0x10100);
    int*   nmt      = (int*)  (ws + 0x10180);
    int*   te       = (int*)  (ws + 0x10200);
    int*   tr0      = (int*)  (ws + 0x10400);
    int*   trn      = (int*)  (ws + 0x10600);
    int*   pair_tok = (int*)  (ws + 0x10800);
    float* pair_w   = (float*)(ws + 0x18800);
    unsigned short* gated = (unsigned short*)(ws + 0x21000);    // 8192*768*2 = 12.6MB
    unsigned short* xb    = (unsigned short*)(ws + 0xC60000);   // 2048*2048*2 = 8MB

    hipMemsetAsync(d_out, 0, (size_t)out_size*sizeof(float), stream);
    hipMemsetAsync(counts, 0, NEXPERT*sizeof(int), stream);

    cvt_x_k  <<<T_TOKENS*HIDDEN/(256*8), 256, 0, stream>>>(x, xb);
    router_k <<<T_TOKENS, 64, 0, stream>>>(x, gate, topk_id, topk_w, counts);
    sched_k  <<<1, 64, 0, stream>>>(counts, offs, cursors, nmt, te, tr0, trn);
    scatter_k<<<NPAIRS/256, 256, 0, stream>>>(topk_id, topk_w, cursors, pair_tok, pair_w);
    gemm1_k  <<<MT_MAX*NT1, 256, 0, stream>>>(xb, gup, nmt, te, tr0, trn, pair_tok, pair_w, gated);
    gemm2_k  <<<MT_MAX*NT2, 256, 0, stream>>>(gated, down, nmt, te, tr0, trn, pair_tok, out);
}